// Round 1
// baseline (98.462 us; speedup 1.0000x reference)
//
#include <hip/hip_runtime.h>
#include <math.h>

// RansacRouting: B=32, I=1152, O=10, D=16, H=10, S=922
// v[b,o,:] == Mu[b,o,:,h*], h* = argmin_h loss.  Mu over subset computed via
// complement (230 elems): num_h = tot - sum_{i in complement_h} vn_i * u_i.
//
// This version: no u_s LDS staging (rows live in registers, 3/thread at
// NT=384); complement gather reads global (L2-hot). LDS 81.7KB -> ~7.8KB
// so 2 blocks/CU co-reside (12 waves/CU vs 8) and the 320-block grid fits
// in one scheduling round (no 64-block tail).

#define B_    32
#define I_    1152
#define O_    10
#define D_    16
#define H_    10
#define S_    922
#define COMP  230     // I_ - S_
#define MASKW 36      // 1152/32
#define NT    384
#define NW    6       // waves per block
#define RPT   3       // rows per thread: 1152/384

// ---- wave64 sum via DPP (VALU pipe, no LDS) -- result valid in lane 63 ----
template <int CTRL, int ROWM>
static __device__ __forceinline__ float dpp_f(float v) {
    return __int_as_float(__builtin_amdgcn_update_dpp(
        0, __float_as_int(v), CTRL, ROWM, 0xf, true));
}
static __device__ __forceinline__ float wave_sum_f32(float v) {
    v += dpp_f<0x111, 0xf>(v);   // row_shr:1
    v += dpp_f<0x112, 0xf>(v);   // row_shr:2
    v += dpp_f<0x114, 0xf>(v);   // row_shr:4
    v += dpp_f<0x118, 0xf>(v);   // row_shr:8
    v += dpp_f<0x142, 0xa>(v);   // row_bcast15 -> rows 1,3
    v += dpp_f<0x143, 0xc>(v);   // row_bcast31 -> rows 2,3
    return v;                    // lane 63 holds the total
}
template <int CTRL, int ROWM>
static __device__ __forceinline__ double dpp_d(double v) {
    long long x = __double_as_longlong(v);
    int lo = (int)(unsigned)(x & 0xffffffffLL);
    int hi = (int)(x >> 32);
    lo = __builtin_amdgcn_update_dpp(0, lo, CTRL, ROWM, 0xf, true);
    hi = __builtin_amdgcn_update_dpp(0, hi, CTRL, ROWM, 0xf, true);
    return __longlong_as_double((long long)(unsigned)lo | ((long long)hi << 32));
}
static __device__ __forceinline__ double wave_sum_f64(double v) {
    v += dpp_d<0x111, 0xf>(v);
    v += dpp_d<0x112, 0xf>(v);
    v += dpp_d<0x114, 0xf>(v);
    v += dpp_d<0x118, 0xf>(v);
    v += dpp_d<0x142, 0xa>(v);
    v += dpp_d<0x143, 0xc>(v);
    return v;
}

__global__ __launch_bounds__(NT, 3) void ransac_kernel(
    const float* __restrict__ up,      // [B,I,O,D]
    const int*   __restrict__ sidx,    // [B,S,O,H]
    float*       __restrict__ out)     // [B,O,D]
{
    __shared__ unsigned       mask[H_][MASKW];     // 1440 B
    __shared__ int            ccount[H_];          // 40
    __shared__ unsigned short clist[H_][COMP];     // 4600
    __shared__ float          Mu_s[H_][D_];        // 640
    __shared__ float          totred[NW][17];      // 408
    __shared__ float          tot[17];             // [0..15]=sum vn*u_d, [16]=sum vn
    __shared__ double         lpart[H_][NW];       // 480
    __shared__ double         losses[H_];          // 80
    __shared__ int            hstar;

    // XCD-aware mapping: the 10 o-blocks of one b share an XCD (L2 reuse)
    const int blk = blockIdx.x;
    const int xcd = blk & 7, g = blk >> 3;       // g in [0,40)
    const int b   = xcd + 8 * (g / O_);
    const int o   = g - O_ * (g / O_);
    const int bo  = b * O_ + o;

    const int tid  = threadIdx.x;
    const int lane = tid & 63;
    const int wv   = tid >> 6;

    // --- zero masks / counters ---
    for (int j = tid; j < H_ * MASKW; j += NT) ((unsigned*)mask)[j] = 0u;
    if (tid < H_) ccount[tid] = 0;

    // --- issue this thread's 3 row loads early (latency hides under scatter) ---
    const float* ub = up + ((size_t)b * I_ * O_ + o) * D_;
    float4 R[RPT][4];
    #pragma unroll
    for (int r = 0; r < RPT; ++r) {
        const float4* p = (const float4*)(ub + (size_t)(tid + r * NT) * (O_ * D_));
        R[r][0] = p[0]; R[r][1] = p[1]; R[r][2] = p[2]; R[r][3] = p[3];
    }

    __syncthreads();   // mask/ccount zeroed

    // --- scatter hypothesis membership bits (one s per thread, 5x int2) ---
    const int* sb = sidx + (size_t)b * (S_ * O_ * H_) + o * H_;
    for (int s = tid; s < S_; s += NT) {
        const int2* ps = (const int2*)(sb + (size_t)s * (O_ * H_));  // 8B-aligned
        int2 a0 = ps[0], a1 = ps[1], a2 = ps[2], a3 = ps[3], a4 = ps[4];
        int v[10] = {a0.x, a0.y, a1.x, a1.y, a2.x, a2.y, a3.x, a3.y, a4.x, a4.y};
        #pragma unroll
        for (int h = 0; h < H_; ++h)
            atomicOr(&mask[h][v[h] >> 5], 1u << (v[h] & 31));
    }

    // --- tot = sum_i vn_i * u_i  (from register rows) ---
    float acc[17];
    #pragma unroll
    for (int d = 0; d < 17; ++d) acc[d] = 0.f;
    #pragma unroll
    for (int r = 0; r < RPT; ++r) {
        float4 q0 = R[r][0], q1 = R[r][1], q2 = R[r][2], q3 = R[r][3];
        float s = q0.x*q0.x + q0.y*q0.y + q0.z*q0.z + q0.w*q0.w
                + q1.x*q1.x + q1.y*q1.y + q1.z*q1.z + q1.w*q1.w
                + q2.x*q2.x + q2.y*q2.y + q2.z*q2.z + q2.w*q2.w
                + q3.x*q3.x + q3.y*q3.y + q3.z*q3.z + q3.w*q3.w;
        float vn = sqrtf(s);
        acc[ 0] = fmaf(vn, q0.x, acc[ 0]); acc[ 1] = fmaf(vn, q0.y, acc[ 1]);
        acc[ 2] = fmaf(vn, q0.z, acc[ 2]); acc[ 3] = fmaf(vn, q0.w, acc[ 3]);
        acc[ 4] = fmaf(vn, q1.x, acc[ 4]); acc[ 5] = fmaf(vn, q1.y, acc[ 5]);
        acc[ 6] = fmaf(vn, q1.z, acc[ 6]); acc[ 7] = fmaf(vn, q1.w, acc[ 7]);
        acc[ 8] = fmaf(vn, q2.x, acc[ 8]); acc[ 9] = fmaf(vn, q2.y, acc[ 9]);
        acc[10] = fmaf(vn, q2.z, acc[10]); acc[11] = fmaf(vn, q2.w, acc[11]);
        acc[12] = fmaf(vn, q3.x, acc[12]); acc[13] = fmaf(vn, q3.y, acc[13]);
        acc[14] = fmaf(vn, q3.z, acc[14]); acc[15] = fmaf(vn, q3.w, acc[15]);
        acc[16] += vn;
    }
    #pragma unroll
    for (int d = 0; d < 17; ++d) acc[d] = wave_sum_f32(acc[d]);
    if (lane == 63) {
        #pragma unroll
        for (int d = 0; d < 17; ++d) totred[wv][d] = acc[d];
    }
    __syncthreads();   // masks + totred complete

    if (tid < 17) {
        float t = 0.f;
        #pragma unroll
        for (int w = 0; w < NW; ++w) t += totred[w][tid];
        tot[tid] = t;
    }

    // --- extract complement index lists (230 per h) ---
    for (int h = wv; h < H_; h += NW) {
        if (lane < MASKW) {
            unsigned m = ~mask[h][lane];
            int cnt = __popc(m);
            int base = atomicAdd(&ccount[h], cnt);
            while (m) {
                int bit = __ffs(m) - 1;
                m &= m - 1u;
                clist[h][base++] = (unsigned short)((lane << 5) + bit);
            }
        }
    }
    __syncthreads();   // clist + tot ready

    // --- Mu per hypothesis via complement gather from GLOBAL (L2-hot) ---
    for (int h = wv; h < H_; h += NW) {
        float na[17];
        #pragma unroll
        for (int d = 0; d < 17; ++d) na[d] = 0.f;
        for (int k = lane; k < COMP; k += 64) {
            int i = clist[h][k];
            const float4* p = (const float4*)(ub + (size_t)i * (O_ * D_));
            float4 q0 = p[0], q1 = p[1], q2 = p[2], q3 = p[3];
            float s = q0.x*q0.x + q0.y*q0.y + q0.z*q0.z + q0.w*q0.w
                    + q1.x*q1.x + q1.y*q1.y + q1.z*q1.z + q1.w*q1.w
                    + q2.x*q2.x + q2.y*q2.y + q2.z*q2.z + q2.w*q2.w
                    + q3.x*q3.x + q3.y*q3.y + q3.z*q3.z + q3.w*q3.w;
            float vn = sqrtf(s);
            na[ 0] = fmaf(vn, q0.x, na[ 0]); na[ 1] = fmaf(vn, q0.y, na[ 1]);
            na[ 2] = fmaf(vn, q0.z, na[ 2]); na[ 3] = fmaf(vn, q0.w, na[ 3]);
            na[ 4] = fmaf(vn, q1.x, na[ 4]); na[ 5] = fmaf(vn, q1.y, na[ 5]);
            na[ 6] = fmaf(vn, q1.z, na[ 6]); na[ 7] = fmaf(vn, q1.w, na[ 7]);
            na[ 8] = fmaf(vn, q2.x, na[ 8]); na[ 9] = fmaf(vn, q2.y, na[ 9]);
            na[10] = fmaf(vn, q2.z, na[10]); na[11] = fmaf(vn, q2.w, na[11]);
            na[12] = fmaf(vn, q3.x, na[12]); na[13] = fmaf(vn, q3.y, na[13]);
            na[14] = fmaf(vn, q3.z, na[14]); na[15] = fmaf(vn, q3.w, na[15]);
            na[16] += vn;
        }
        #pragma unroll
        for (int d = 0; d < 17; ++d) na[d] = wave_sum_f32(na[d]);
        if (lane == 63) {
            float rd = 1.f / (tot[16] - na[16]);
            #pragma unroll
            for (int d = 0; d < D_; ++d)
                Mu_s[h][d] = (tot[d] - na[d]) * rd;
        }
    }
    __syncthreads();   // Mu ready

    // --- loss: h-outer over register-resident rows; Mu broadcast from LDS ---
    float usq[RPT];
    #pragma unroll
    for (int r = 0; r < RPT; ++r) {
        float uq[D_] = {R[r][0].x, R[r][0].y, R[r][0].z, R[r][0].w,
                        R[r][1].x, R[r][1].y, R[r][1].z, R[r][1].w,
                        R[r][2].x, R[r][2].y, R[r][2].z, R[r][2].w,
                        R[r][3].x, R[r][3].y, R[r][3].z, R[r][3].w};
        float s = 0.f;
        #pragma unroll
        for (int d = 0; d < D_; ++d) s = fmaf(uq[d], uq[d], s);
        usq[r] = s;
    }
    for (int h = 0; h < H_; ++h) {
        float4 m0 = *(const float4*)&Mu_s[h][0];
        float4 m1 = *(const float4*)&Mu_s[h][4];
        float4 m2 = *(const float4*)&Mu_s[h][8];
        float4 m3 = *(const float4*)&Mu_s[h][12];
        float mv[D_] = {m0.x, m0.y, m0.z, m0.w, m1.x, m1.y, m1.z, m1.w,
                        m2.x, m2.y, m2.z, m2.w, m3.x, m3.y, m3.z, m3.w};
        float musq = 0.f;
        #pragma unroll
        for (int d = 0; d < D_; ++d) musq = fmaf(mv[d], mv[d], musq);
        double l = 0.0;
        #pragma unroll
        for (int r = 0; r < RPT; ++r) {
            float uq[D_] = {R[r][0].x, R[r][0].y, R[r][0].z, R[r][0].w,
                            R[r][1].x, R[r][1].y, R[r][1].z, R[r][1].w,
                            R[r][2].x, R[r][2].y, R[r][2].z, R[r][2].w,
                            R[r][3].x, R[r][3].y, R[r][3].z, R[r][3].w};
            float dot = 0.f;
            #pragma unroll
            for (int d = 0; d < D_; ++d) dot = fmaf(uq[d], mv[d], dot);
            float d2 = fmaf(-2.f, dot, usq[r] + musq);
            l += (double)sqrtf(fmaxf(d2, 0.f));
        }
        l = wave_sum_f64(l);
        if (lane == 63) lpart[h][wv] = l;
    }
    __syncthreads();

    if (tid < H_) {
        double t = 0.0;
        #pragma unroll
        for (int w = 0; w < NW; ++w) t += lpart[tid][w];
        losses[tid] = t;
    }
    __syncthreads();
    if (tid == 0) {
        int best = 0; double bl = losses[0];
        #pragma unroll
        for (int h = 1; h < H_; ++h)
            if (losses[h] < bl) { bl = losses[h]; best = h; }
        hstar = best;
    }
    __syncthreads();
    if (tid < D_)
        out[(size_t)bo * D_ + tid] = Mu_s[hstar][tid];
}

extern "C" void kernel_launch(void* const* d_in, const int* in_sizes, int n_in,
                              void* d_out, int out_size, void* d_ws, size_t ws_size,
                              hipStream_t stream) {
    const float* up   = (const float*)d_in[0];
    const int*   sidx = (const int*)d_in[1];
    float*       out  = (float*)d_out;
    ransac_kernel<<<B_ * O_, NT, 0, stream>>>(up, sidx, out);
}